// Round 22
// baseline (199.160 us; speedup 1.0000x reference)
//
#include <hip/hip_runtime.h>
#include <hip/hip_fp16.h>

#define REP10(X) X(0) X(1) X(2) X(3) X(4) X(5) X(6) X(7) X(8) X(9)
#define REP5(X)  X(0) X(1) X(2) X(3) X(4)

typedef __attribute__((ext_vector_type(2))) float v2;
typedef _Float16 h2 __attribute__((ext_vector_type(2)));

#define SMX 136   // smm pair-row stride (positions)

// ---------------------------------------------------------------------------
// prep_kernel: per stage (stride 1024 floats in consts):
// [0..10) scale | [10..20) shift2 | [20..70) adw2 | [70..80) adb2 (log2e) |
// [80..100) abp[o*10+i] | [100..500) aKp fp32 (stage1 path) |
// [512..612) aKh2: 200 half2, idx ((h*5+pc)*2+o)*10+i |
// [640..765) ckh2: 250 half2, idx (w*5+pc)*10+c
// ---------------------------------------------------------------------------
__device__ __forceinline__ void fold_stage(
    float* dst, const float* g, const float* be, const float* mn,
    const float* vr, const float* cb, const float* adw, const float* adb,
    const float* aK, const float* ab, const float* ckfull, int CIN)
{
  const int tid = threadIdx.x;
  if (tid < 10) {
    const float sc = g[tid] * rsqrtf(vr[tid] + 1e-3f);
    dst[tid]      = sc;
    dst[10 + tid] = (cb[tid] - mn[tid]) * sc + be[tid];
    dst[70 + tid] = adb[tid] * 1.44269504088896340736f;
  }
  if (tid >= 10 && tid < 60)
    dst[10 + tid] = adw[tid - 10] * 1.44269504088896340736f;
  if (tid < 20)
    dst[80 + tid] = ab[(tid % 10) * 2 + tid / 10];
  const int n = 2 * CIN * 2 * 10;
  for (int idx = tid; idx < n; idx += 64) {
    const int i  = idx % 10;
    const int r  = idx / 10;
    const int o  = r % 2;
    const int r2 = r / 2;
    const int ci = r2 % CIN;
    const int h  = r2 / CIN;
    dst[100 + idx] = aK[((i * 2 + h) * CIN + ci) * 2 + o];
  }
  if (ckfull) {   // fp16 ci-pair-major copies for the dot2 path (CIN=10)
    __half2* aKh = (__half2*)(dst + 512);
    for (int idx = tid; idx < 200; idx += 64) {
      const int i    = idx % 10;
      const int rest = idx / 10;
      const int o    = rest & 1;
      const int hp   = rest >> 1;
      const int pc   = hp % 5;
      const int h    = hp / 5;
      const float a0 = aK[((i * 2 + h) * 10 + 2 * pc) * 2 + o];
      const float a1 = aK[((i * 2 + h) * 10 + 2 * pc + 1) * 2 + o];
      aKh[idx] = __float22half2_rn(make_float2(a0, a1));
    }
    __half2* ckh = (__half2*)(dst + 640);
    for (int idx = tid; idx < 250; idx += 64) {
      const int c  = idx % 10;
      const int wp = idx / 10;
      const int pc = wp % 5;
      const int w  = wp / 5;
      const float k0 = ckfull[(w * 10 + 2 * pc) * 10 + c];
      const float k1 = ckfull[(w * 10 + 2 * pc + 1) * 10 + c];
      ckh[idx] = __float22half2_rn(make_float2(k0, k1));
    }
  }
}

__global__ void prep_kernel(
    const float* g1, const float* be1, const float* m1, const float* v1,
    const float* cb1, const float* a1dw, const float* a1db,
    const float* a1K, const float* a1b,
    const float* g2, const float* be2, const float* m2, const float* v2_,
    const float* cb2, const float* a2dw, const float* a2db,
    const float* a2K, const float* a2b, const float* c2k,
    const float* g3, const float* be3, const float* m3, const float* v3,
    const float* cb3, const float* a3dw, const float* a3db,
    const float* a3K, const float* a3b, const float* c3k,
    float* consts)
{
  fold_stage(consts,        g1, be1, m1, v1,  cb1, a1dw, a1db, a1K, a1b,
             nullptr, 1);
  fold_stage(consts + 1024, g2, be2, m2, v2_, cb2, a2dw, a2db, a2K, a2b,
             c2k, 10);
  fold_stage(consts + 2048, g3, be3, m3, v3,  cb3, a3dw, a3db, a3K, a3b,
             c3k, 10);
}

// ---------------------------------------------------------------------------
// stage_kernel: R21 structure + R22 instruction diet:
//  (1) CIN=10: input tile staged in LDS (xt, 5.4KB, zero-padded) -> ein/conv
//      reads are ds_read_b32 with immediate offsets; kills ~80 instr/thread
//      of 64-bit global address math (R21 evidence: dur tracks instr count).
//  (2) softmax max-tree removed (shift-invariant; logits |y|<~3; R9-validated).
// fp16 paired intermediates [b][p][o][t]; dot2 math throughout CIN=10.
// ---------------------------------------------------------------------------
template <int CIN>
__global__ __launch_bounds__(128) void stage_kernel(
    const void* __restrict__ inv_, __half2* __restrict__ outp, int Tout,
    const float* __restrict__ ck, const float* __restrict__ cst)
{
  __shared__ float smm[5 * SMX * 2];
  __shared__ h2 xt[10 * SMX];       // staged input tile (CIN=10 only)
  const int tid = threadIdx.x;      // 0..127
  const int o   = blockIdx.y;
  const int t0  = blockIdx.x * 128;
  const int Tin = Tout + 4;

  const float* __restrict__ inf =
      (CIN == 1) ? ((const float*)inv_) + (size_t)blockIdx.z * 2000 : nullptr;
  const h2* __restrict__ inx =
      (CIN == 1) ? nullptr : ((const h2*)inv_) + (size_t)blockIdx.z * 10000;

  const float* __restrict__ scale  = cst;
  const float* __restrict__ shift2 = cst + 10;
  const float* __restrict__ adw2   = cst + 20;
  const float* __restrict__ adb2   = cst + 70;
  const float* __restrict__ abp    = cst + 80;
  const float* __restrict__ aKp    = cst + 100;
  const h2* __restrict__ aKh = (const h2*)(cst + 512);
  const h2* __restrict__ ckh = (const h2*)(cst + 640);

  // ---- Phase 0 (CIN=10): stage input tile rows into LDS, zero-padded
  if constexpr (CIN == 10) {
#pragma unroll
    for (int r = 0; r < 10; ++r)
      for (int lt = tid; lt < 132; lt += 128) {
        const int t = t0 + lt;
        xt[r * SMX + lt] = (t < Tin) ? inx[r * 1000 + t] : (h2){0, 0};
      }
    __syncthreads();
  }

  // ---- Phase A: einsum m -> smm (pair-interleaved), positions [t0,t0+132)
  for (int lt = tid; lt < 132; lt += 128) {
    const int t = t0 + lt;
    if constexpr (CIN == 1) {
      if (t < Tin) {
#define DECLM(p) v2 mp##p = *reinterpret_cast<const v2*>(abp + o * 10 + 2 * p);
        REP5(DECLM)
#undef DECLM
#pragma unroll
        for (int h = 0; h < 2; ++h) {
          const float xin = inf[h * 1000 + t];
          const v2 xs = {xin, xin};
          const float* kb = aKp + (h * 2 + o) * 10;
#define FMAM(p) mp##p = __builtin_elementwise_fma(                             \
              xs, *reinterpret_cast<const v2*>(kb + 2 * p), mp##p);
          REP5(FMAM)
#undef FMAM
        }
#define STM(p) *reinterpret_cast<v2*>(&smm[(p * SMX + lt) * 2]) = mp##p;
        REP5(STM)
#undef STM
      }
    } else {
#define DECLM(i) float m##i = abp[o * 10 + i];
      REP10(DECLM)
#undef DECLM
#pragma unroll
      for (int h = 0; h < 2; ++h)
#pragma unroll
        for (int pc = 0; pc < 5; ++pc) {
          const h2 xp = xt[(pc * 2 + h) * SMX + lt];
          const h2* kb = aKh + ((h * 5 + pc) * 2 + o) * 10;
#define DOTM(i) m##i = __builtin_amdgcn_fdot2(xp, kb[i], m##i, false);
          REP10(DOTM)
#undef DOTM
        }
      { const v2 s0 = {m0, m1}; *reinterpret_cast<v2*>(&smm[(0*SMX+lt)*2]) = s0;
        const v2 s1 = {m2, m3}; *reinterpret_cast<v2*>(&smm[(1*SMX+lt)*2]) = s1;
        const v2 s2 = {m4, m5}; *reinterpret_cast<v2*>(&smm[(2*SMX+lt)*2]) = s2;
        const v2 s3 = {m6, m7}; *reinterpret_cast<v2*>(&smm[(3*SMX+lt)*2]) = s3;
        const v2 s4 = {m8, m9}; *reinterpret_cast<v2*>(&smm[(4*SMX+lt)*2]) = s4; }
    }
  }
  __syncthreads();

  // ---- Phase B: 1 output/thread (no barriers below -> early-out safe)
  const int tt = t0 + tid;
  if (tt >= Tout) return;

  // depthwise logits: 25x ds_read_b64 + packed FMA (smm is fp32)
#define DECLY(p) v2 yp##p = *reinterpret_cast<const v2*>(adb2 + 2 * p);
  REP5(DECLY)
#undef DECLY
#pragma unroll
  for (int w = 0; w < 5; ++w) {
    const float* aw = adw2 + w * 10;
#define FMAY(p) { const v2 sv =                                                \
        *reinterpret_cast<const v2*>(&smm[(p * SMX + tid + w) * 2]);           \
      yp##p = __builtin_elementwise_fma(                                       \
          sv, *reinterpret_cast<const v2*>(aw + 2 * p), yp##p); }
    REP5(FMAY)
#undef FMAY
  }

  // conv (1,5) valid, CIN -> 10
#define DECLAS(i) float a##i = 0.f;
  REP10(DECLAS)
#undef DECLAS
  if constexpr (CIN == 1) {
    const float* __restrict__ cinb = inf + o * 1000 + tt;
#pragma unroll
    for (int w = 0; w < 5; ++w) {
      const float xin = cinb[w];
      const float* kb = ck + w * 10;
#define FMAC(i) a##i = fmaf(xin, kb[i], a##i);
      REP10(FMAC)
#undef FMAC
    }
  } else {
#pragma unroll
    for (int w = 0; w < 5; ++w)
#pragma unroll
      for (int pc = 0; pc < 5; ++pc) {
        const h2 xp = xt[(pc * 2 + o) * SMX + tid + w];
        const h2* kb = ckh + (w * 5 + pc) * 10;
#define DOTC(i) a##i = __builtin_amdgcn_fdot2(xp, kb[i], a##i, false);
        REP10(DOTC)
#undef DOTC
      }
  }

  // softmax over 10 heads via native exp2; NO max-subtraction (shift-
  // invariant, logits O(1), R9-validated numerically)
  const float y0 = yp0.x, y1 = yp0.y, y2 = yp1.x, y3 = yp1.y, y4 = yp2.x,
              y5 = yp2.y, y6 = yp3.x, y7 = yp3.y, y8 = yp4.x, y9 = yp4.y;
#define DECLE(i) const float e##i = exp2f(y##i);
  REP10(DECLE)
#undef DECLE
  const float sm  = e0 + e1 + e2 + e3 + e4 + e5 + e6 + e7 + e8 + e9;
  const float inv = __builtin_amdgcn_rcpf(sm);

  // packed epilogue + fp16 pair store: out[b][p][o][t]
  __half2* __restrict__ ob =
      outp + (size_t)blockIdx.z * 10000 + o * 1000 + tt;
#define STO(p, aa, ab_, ea, eb) {                                              \
    v2 av = {aa, ab_};                                                         \
    v2 bv = __builtin_elementwise_fma(                                         \
        av, *reinterpret_cast<const v2*>(scale + 2 * p),                       \
        *reinterpret_cast<const v2*>(shift2 + 2 * p));                         \
    bv = __builtin_elementwise_max(bv, 0.2f * bv);                             \
    ob[p * 2000] = __float22half2_rn(make_float2(bv.x * ea * inv,              \
                                                 bv.y * eb * inv)); }
  STO(0, a0, a1, e0, e1) STO(1, a2, a3, e2, e3) STO(2, a4, a5, e4, e5)
  STO(3, a6, a7, e6, e7) STO(4, a8, a9, e8, e9)
#undef STO
}

// ---------------------------------------------------------------------------
// final_kernel: conv4 (2,1) -> lrelu -> dot(dns_w) -> block reduce -> out[b].
// Consumes fp16 paired h3 [b][p][o][t]; fully packed math. (R19-validated.)
// ---------------------------------------------------------------------------
__global__ __launch_bounds__(256) void final_kernel(
    const __half2* __restrict__ h3, const float* __restrict__ c4k,
    const float* __restrict__ c4b, const float* __restrict__ dnsw,
    const float* __restrict__ dnsb, float* __restrict__ outp, int b0)
{
  __shared__ float red[4];
  const int tid = threadIdx.x;
  const __half2* __restrict__ hb = h3 + (size_t)blockIdx.x * 10000;
  v2 dotv = {0.f, 0.f};
#pragma unroll 1
  for (int t = tid; t < 988; t += 256) {
#define LDX(p)                                                                 \
    const float2 fa##p = __half22float2(hb[(p*2+0)*1000 + t]);                 \
    const float2 fc##p = __half22float2(hb[(p*2+1)*1000 + t]);
    REP5(LDX)
#undef LDX
    const float* __restrict__ dwp = dnsw + t * 20;
#pragma unroll
    for (int q = 0; q < 10; ++q) {
      v2 acc = *reinterpret_cast<const v2*>(c4b + 2 * q);
      const float* kq = c4k + 2 * q;
#define FMA4(p) {                                                              \
      const v2 s0 = {fa##p.x, fa##p.x}, s1 = {fa##p.y, fa##p.y};               \
      const v2 s2 = {fc##p.x, fc##p.x}, s3 = {fc##p.y, fc##p.y};               \
      acc = __builtin_elementwise_fma(                                         \
          s0, *reinterpret_cast<const v2*>(kq + (2*p) * 20), acc);             \
      acc = __builtin_elementwise_fma(                                         \
          s1, *reinterpret_cast<const v2*>(kq + (2*p+1) * 20), acc);           \
      acc = __builtin_elementwise_fma(                                         \
          s2, *reinterpret_cast<const v2*>(kq + (10+2*p) * 20), acc);          \
      acc = __builtin_elementwise_fma(                                         \
          s3, *reinterpret_cast<const v2*>(kq + (10+2*p+1) * 20), acc); }
      REP5(FMA4)
#undef FMA4
      acc  = __builtin_elementwise_max(acc, 0.2f * acc);
      dotv = __builtin_elementwise_fma(
          acc, *reinterpret_cast<const v2*>(dwp + 2 * q), dotv);
    }
  }
  float partial = dotv.x + dotv.y;
#pragma unroll
  for (int off = 32; off > 0; off >>= 1)
    partial += __shfl_down(partial, off, 64);
  if ((tid & 63) == 0) red[tid >> 6] = partial;
  __syncthreads();
  if (tid == 0)
    outp[b0 + blockIdx.x] = red[0] + red[1] + red[2] + red[3] + dnsb[0];
}

extern "C" void kernel_launch(void* const* d_in, const int* in_sizes, int n_in,
                              void* d_out, int out_size, void* d_ws, size_t ws_size,
                              hipStream_t stream) {
  const float* p[35];
  for (int i = 0; i < 35; ++i) p[i] = (const float*)d_in[i];
  const int B = in_sizes[0] / 2000;

  // ws: consts[3072 floats] | hA | hB (fp16 paired tensors, 10000 half2/b)
  float* consts = (float*)d_ws;
  __half2* hA   = (__half2*)(consts + 3072);
  const size_t avail = ws_size - 3072u * 4u;
  int CH = 1024;
  if (CH > B) CH = B;
  while ((size_t)CH * 80000ull > avail && CH > 1) CH >>= 1;
  __half2* hB = hA + (size_t)CH * 10000;

  prep_kernel<<<dim3(1), dim3(64), 0, stream>>>(
      p[9], p[10], p[11], p[12], p[2], p[25], p[26], p[23], p[24],
      p[13], p[14], p[15], p[16], p[4], p[29], p[30], p[27], p[28], p[3],
      p[17], p[18], p[19], p[20], p[6], p[33], p[34], p[31], p[32], p[5],
      consts);

  for (int b0 = 0; b0 < B; b0 += CH) {
    const int cc = (B - b0 < CH) ? (B - b0) : CH;
    // stage1: x -> hA (Tout=996), fp32 x input, fp16 paired output
    stage_kernel<1><<<dim3(8, 2, cc), dim3(128), 0, stream>>>(
        (const void*)(p[0] + (size_t)b0 * 2000), hA, 996, p[1], consts);
    // stage2: hA -> hB (Tout=992), dot2 path
    stage_kernel<10><<<dim3(8, 2, cc), dim3(128), 0, stream>>>(
        (const void*)hA, hB, 992, nullptr, consts + 1024);
    // stage3: hB -> hA (Tout=988), dot2 path
    stage_kernel<10><<<dim3(8, 2, cc), dim3(128), 0, stream>>>(
        (const void*)hB, hA, 988, nullptr, consts + 2048);
    // conv4 + dense head (writes out[b] directly)
    final_kernel<<<dim3(cc), dim3(256), 0, stream>>>(
        hA, p[7], p[8], p[21], p[22], (float*)d_out, b0);
  }
}

// Round 23
// 154.149 us; speedup vs baseline: 1.2920x; 1.2920x over previous
//
#include <hip/hip_runtime.h>
#include <hip/hip_fp16.h>

#define REP10(X) X(0) X(1) X(2) X(3) X(4) X(5) X(6) X(7) X(8) X(9)
#define REP5(X)  X(0) X(1) X(2) X(3) X(4)

typedef __attribute__((ext_vector_type(2))) float v2;
typedef _Float16 h2 __attribute__((ext_vector_type(2)));

#define SMX 136   // smm pair-row stride (positions)

// ---------------------------------------------------------------------------
// prep_kernel: per stage (stride 1024 floats in consts):
// [0..10) scale | [10..20) shift2 | [20..70) adw2 | [70..80) adb2 (log2e) |
// [80..100) abp[o*10+i] | [100..500) aKp fp32 (stage1 path) |
// [512..612) aKh2: 200 half2, idx ((h*5+pc)*2+o)*10+i |
// [640..765) ckh2: 250 half2, idx (w*5+pc)*10+c
// ---------------------------------------------------------------------------
__device__ __forceinline__ void fold_stage(
    float* dst, const float* g, const float* be, const float* mn,
    const float* vr, const float* cb, const float* adw, const float* adb,
    const float* aK, const float* ab, const float* ckfull, int CIN)
{
  const int tid = threadIdx.x;
  if (tid < 10) {
    const float sc = g[tid] * rsqrtf(vr[tid] + 1e-3f);
    dst[tid]      = sc;
    dst[10 + tid] = (cb[tid] - mn[tid]) * sc + be[tid];
    dst[70 + tid] = adb[tid] * 1.44269504088896340736f;
  }
  if (tid >= 10 && tid < 60)
    dst[10 + tid] = adw[tid - 10] * 1.44269504088896340736f;
  if (tid < 20)
    dst[80 + tid] = ab[(tid % 10) * 2 + tid / 10];
  const int n = 2 * CIN * 2 * 10;
  for (int idx = tid; idx < n; idx += 64) {
    const int i  = idx % 10;
    const int r  = idx / 10;
    const int o  = r % 2;
    const int r2 = r / 2;
    const int ci = r2 % CIN;
    const int h  = r2 / CIN;
    dst[100 + idx] = aK[((i * 2 + h) * CIN + ci) * 2 + o];
  }
  if (ckfull) {   // fp16 ci-pair-major copies for the dot2 path (CIN=10)
    __half2* aKh = (__half2*)(dst + 512);
    for (int idx = tid; idx < 200; idx += 64) {
      const int i    = idx % 10;
      const int rest = idx / 10;
      const int o    = rest & 1;
      const int hp   = rest >> 1;
      const int pc   = hp % 5;
      const int h    = hp / 5;
      const float a0 = aK[((i * 2 + h) * 10 + 2 * pc) * 2 + o];
      const float a1 = aK[((i * 2 + h) * 10 + 2 * pc + 1) * 2 + o];
      aKh[idx] = __float22half2_rn(make_float2(a0, a1));
    }
    __half2* ckh = (__half2*)(dst + 640);
    for (int idx = tid; idx < 250; idx += 64) {
      const int c  = idx % 10;
      const int wp = idx / 10;
      const int pc = wp % 5;
      const int w  = wp / 5;
      const float k0 = ckfull[(w * 10 + 2 * pc) * 10 + c];
      const float k1 = ckfull[(w * 10 + 2 * pc + 1) * 10 + c];
      ckh[idx] = __float22half2_rn(make_float2(k0, k1));
    }
  }
}

__global__ void prep_kernel(
    const float* g1, const float* be1, const float* m1, const float* v1,
    const float* cb1, const float* a1dw, const float* a1db,
    const float* a1K, const float* a1b,
    const float* g2, const float* be2, const float* m2, const float* v2_,
    const float* cb2, const float* a2dw, const float* a2db,
    const float* a2K, const float* a2b, const float* c2k,
    const float* g3, const float* be3, const float* m3, const float* v3,
    const float* cb3, const float* a3dw, const float* a3db,
    const float* a3K, const float* a3b, const float* c3k,
    float* consts)
{
  fold_stage(consts,        g1, be1, m1, v1,  cb1, a1dw, a1db, a1K, a1b,
             nullptr, 1);
  fold_stage(consts + 1024, g2, be2, m2, v2_, cb2, a2dw, a2db, a2K, a2b,
             c2k, 10);
  fold_stage(consts + 2048, g3, be3, m3, v3,  cb3, a3dw, a3db, a3K, a3b,
             c3k, 10);
}

// ---------------------------------------------------------------------------
// stage_kernel: R21 structure EXACTLY (128-thr block, tile 128, 1 output/
// thread, LDS = smm only, fp16 paired intermediates [b][p][o][t], dot2 math
// for CIN=10 -- validated 154.9us total). R23 single change: softmax
// max-tree removed (shift-invariant; logits O(1); numerics validated in R22
// where absmax stayed 1.5e-5 with this active). R22's LDS input staging
// REVERTED (it added a copy pass + barrier: 51.5 -> 71.8us).
// ---------------------------------------------------------------------------
template <int CIN>
__global__ __launch_bounds__(128) void stage_kernel(
    const void* __restrict__ inv_, __half2* __restrict__ outp, int Tout,
    const float* __restrict__ ck, const float* __restrict__ cst)
{
  __shared__ float smm[5 * SMX * 2];
  const int tid = threadIdx.x;      // 0..127
  const int o   = blockIdx.y;
  const int t0  = blockIdx.x * 128;
  const int Tin = Tout + 4;

  const float* __restrict__ inf =
      (CIN == 1) ? ((const float*)inv_) + (size_t)blockIdx.z * 2000 : nullptr;
  const h2* __restrict__ inx =
      (CIN == 1) ? nullptr : ((const h2*)inv_) + (size_t)blockIdx.z * 10000;

  const float* __restrict__ scale  = cst;
  const float* __restrict__ shift2 = cst + 10;
  const float* __restrict__ adw2   = cst + 20;
  const float* __restrict__ adb2   = cst + 70;
  const float* __restrict__ abp    = cst + 80;
  const float* __restrict__ aKp    = cst + 100;
  const h2* __restrict__ aKh = (const h2*)(cst + 512);
  const h2* __restrict__ ckh = (const h2*)(cst + 640);

  // ---- Phase A: einsum m -> smm (pair-interleaved), positions [t0,t0+132)
  for (int lt = tid; lt < 132; lt += 128) {
    const int t = t0 + lt;
    if (t < Tin) {
      if constexpr (CIN == 1) {
#define DECLM(p) v2 mp##p = *reinterpret_cast<const v2*>(abp + o * 10 + 2 * p);
        REP5(DECLM)
#undef DECLM
#pragma unroll
        for (int h = 0; h < 2; ++h) {
          const float xin = inf[h * 1000 + t];
          const v2 xs = {xin, xin};
          const float* kb = aKp + (h * 2 + o) * 10;
#define FMAM(p) mp##p = __builtin_elementwise_fma(                             \
              xs, *reinterpret_cast<const v2*>(kb + 2 * p), mp##p);
          REP5(FMAM)
#undef FMAM
        }
#define STM(p) *reinterpret_cast<v2*>(&smm[(p * SMX + lt) * 2]) = mp##p;
        REP5(STM)
#undef STM
      } else {
#define DECLM(i) float m##i = abp[o * 10 + i];
        REP10(DECLM)
#undef DECLM
#pragma unroll
        for (int h = 0; h < 2; ++h)
#pragma unroll
          for (int pc = 0; pc < 5; ++pc) {
            const h2 xp = inx[(pc * 2 + h) * 1000 + t];
            const h2* kb = aKh + ((h * 5 + pc) * 2 + o) * 10;
#define DOTM(i) m##i = __builtin_amdgcn_fdot2(xp, kb[i], m##i, false);
            REP10(DOTM)
#undef DOTM
          }
        { const v2 s0 = {m0, m1}; *reinterpret_cast<v2*>(&smm[(0*SMX+lt)*2]) = s0;
          const v2 s1 = {m2, m3}; *reinterpret_cast<v2*>(&smm[(1*SMX+lt)*2]) = s1;
          const v2 s2 = {m4, m5}; *reinterpret_cast<v2*>(&smm[(2*SMX+lt)*2]) = s2;
          const v2 s3 = {m6, m7}; *reinterpret_cast<v2*>(&smm[(3*SMX+lt)*2]) = s3;
          const v2 s4 = {m8, m9}; *reinterpret_cast<v2*>(&smm[(4*SMX+lt)*2]) = s4; }
      }
    }
  }
  __syncthreads();

  // ---- Phase B: 1 output/thread (no barriers below -> early-out safe)
  const int tt = t0 + tid;
  if (tt >= Tout) return;

  // depthwise logits: 25x ds_read_b64 + packed FMA (smm is fp32)
#define DECLY(p) v2 yp##p = *reinterpret_cast<const v2*>(adb2 + 2 * p);
  REP5(DECLY)
#undef DECLY
#pragma unroll
  for (int w = 0; w < 5; ++w) {
    const float* aw = adw2 + w * 10;
#define FMAY(p) { const v2 sv =                                                \
        *reinterpret_cast<const v2*>(&smm[(p * SMX + tid + w) * 2]);           \
      yp##p = __builtin_elementwise_fma(                                       \
          sv, *reinterpret_cast<const v2*>(aw + 2 * p), yp##p); }
    REP5(FMAY)
#undef FMAY
  }

  // conv (1,5) valid, CIN -> 10
#define DECLAS(i) float a##i = 0.f;
  REP10(DECLAS)
#undef DECLAS
  if constexpr (CIN == 1) {
    const float* __restrict__ cinb = inf + o * 1000 + tt;
#pragma unroll
    for (int w = 0; w < 5; ++w) {
      const float xin = cinb[w];
      const float* kb = ck + w * 10;
#define FMAC(i) a##i = fmaf(xin, kb[i], a##i);
      REP10(FMAC)
#undef FMAC
    }
  } else {
#pragma unroll
    for (int w = 0; w < 5; ++w)
#pragma unroll
      for (int pc = 0; pc < 5; ++pc) {
        const h2 xp = inx[(pc * 2 + o) * 1000 + tt + w];
        const h2* kb = ckh + (w * 5 + pc) * 10;
#define DOTC(i) a##i = __builtin_amdgcn_fdot2(xp, kb[i], a##i, false);
        REP10(DOTC)
#undef DOTC
      }
  }

  // softmax over 10 heads via native exp2; NO max-subtraction (shift-
  // invariant, logits O(1), validated in R22: absmax unchanged)
  const float y0 = yp0.x, y1 = yp0.y, y2 = yp1.x, y3 = yp1.y, y4 = yp2.x,
              y5 = yp2.y, y6 = yp3.x, y7 = yp3.y, y8 = yp4.x, y9 = yp4.y;
#define DECLE(i) const float e##i = exp2f(y##i);
  REP10(DECLE)
#undef DECLE
  const float sm  = e0 + e1 + e2 + e3 + e4 + e5 + e6 + e7 + e8 + e9;
  const float inv = __builtin_amdgcn_rcpf(sm);

  // packed epilogue + fp16 pair store: out[b][p][o][t]
  __half2* __restrict__ ob =
      outp + (size_t)blockIdx.z * 10000 + o * 1000 + tt;
#define STO(p, aa, ab_, ea, eb) {                                              \
    v2 av = {aa, ab_};                                                         \
    v2 bv = __builtin_elementwise_fma(                                         \
        av, *reinterpret_cast<const v2*>(scale + 2 * p),                       \
        *reinterpret_cast<const v2*>(shift2 + 2 * p));                         \
    bv = __builtin_elementwise_max(bv, 0.2f * bv);                             \
    ob[p * 2000] = __float22half2_rn(make_float2(bv.x * ea * inv,              \
                                                 bv.y * eb * inv)); }
  STO(0, a0, a1, e0, e1) STO(1, a2, a3, e2, e3) STO(2, a4, a5, e4, e5)
  STO(3, a6, a7, e6, e7) STO(4, a8, a9, e8, e9)
#undef STO
}

// ---------------------------------------------------------------------------
// final_kernel: conv4 (2,1) -> lrelu -> dot(dns_w) -> block reduce -> out[b].
// Consumes fp16 paired h3 [b][p][o][t]; fully packed math. (R19-validated.)
// ---------------------------------------------------------------------------
__global__ __launch_bounds__(256) void final_kernel(
    const __half2* __restrict__ h3, const float* __restrict__ c4k,
    const float* __restrict__ c4b, const float* __restrict__ dnsw,
    const float* __restrict__ dnsb, float* __restrict__ outp, int b0)
{
  __shared__ float red[4];
  const int tid = threadIdx.x;
  const __half2* __restrict__ hb = h3 + (size_t)blockIdx.x * 10000;
  v2 dotv = {0.f, 0.f};
#pragma unroll 1
  for (int t = tid; t < 988; t += 256) {
#define LDX(p)                                                                 \
    const float2 fa##p = __half22float2(hb[(p*2+0)*1000 + t]);                 \
    const float2 fc##p = __half22float2(hb[(p*2+1)*1000 + t]);
    REP5(LDX)
#undef LDX
    const float* __restrict__ dwp = dnsw + t * 20;
#pragma unroll
    for (int q = 0; q < 10; ++q) {
      v2 acc = *reinterpret_cast<const v2*>(c4b + 2 * q);
      const float* kq = c4k + 2 * q;
#define FMA4(p) {                                                              \
      const v2 s0 = {fa##p.x, fa##p.x}, s1 = {fa##p.y, fa##p.y};               \
      const v2 s2 = {fc##p.x, fc##p.x}, s3 = {fc##p.y, fc##p.y};               \
      acc = __builtin_elementwise_fma(                                         \
          s0, *reinterpret_cast<const v2*>(kq + (2*p) * 20), acc);             \
      acc = __builtin_elementwise_fma(                                         \
          s1, *reinterpret_cast<const v2*>(kq + (2*p+1) * 20), acc);           \
      acc = __builtin_elementwise_fma(                                         \
          s2, *reinterpret_cast<const v2*>(kq + (10+2*p) * 20), acc);          \
      acc = __builtin_elementwise_fma(                                         \
          s3, *reinterpret_cast<const v2*>(kq + (10+2*p+1) * 20), acc); }
      REP5(FMA4)
#undef FMA4
      acc  = __builtin_elementwise_max(acc, 0.2f * acc);
      dotv = __builtin_elementwise_fma(
          acc, *reinterpret_cast<const v2*>(dwp + 2 * q), dotv);
    }
  }
  float partial = dotv.x + dotv.y;
#pragma unroll
  for (int off = 32; off > 0; off >>= 1)
    partial += __shfl_down(partial, off, 64);
  if ((tid & 63) == 0) red[tid >> 6] = partial;
  __syncthreads();
  if (tid == 0)
    outp[b0 + blockIdx.x] = red[0] + red[1] + red[2] + red[3] + dnsb[0];
}

extern "C" void kernel_launch(void* const* d_in, const int* in_sizes, int n_in,
                              void* d_out, int out_size, void* d_ws, size_t ws_size,
                              hipStream_t stream) {
  const float* p[35];
  for (int i = 0; i < 35; ++i) p[i] = (const float*)d_in[i];
  const int B = in_sizes[0] / 2000;

  // ws: consts[3072 floats] | hA | hB (fp16 paired tensors, 10000 half2/b)
  float* consts = (float*)d_ws;
  __half2* hA   = (__half2*)(consts + 3072);
  const size_t avail = ws_size - 3072u * 4u;
  int CH = 1024;
  if (CH > B) CH = B;
  while ((size_t)CH * 80000ull > avail && CH > 1) CH >>= 1;
  __half2* hB = hA + (size_t)CH * 10000;

  prep_kernel<<<dim3(1), dim3(64), 0, stream>>>(
      p[9], p[10], p[11], p[12], p[2], p[25], p[26], p[23], p[24],
      p[13], p[14], p[15], p[16], p[4], p[29], p[30], p[27], p[28], p[3],
      p[17], p[18], p[19], p[20], p[6], p[33], p[34], p[31], p[32], p[5],
      consts);

  for (int b0 = 0; b0 < B; b0 += CH) {
    const int cc = (B - b0 < CH) ? (B - b0) : CH;
    // stage1: x -> hA (Tout=996), fp32 x input, fp16 paired output
    stage_kernel<1><<<dim3(8, 2, cc), dim3(128), 0, stream>>>(
        (const void*)(p[0] + (size_t)b0 * 2000), hA, 996, p[1], consts);
    // stage2: hA -> hB (Tout=992), dot2 path
    stage_kernel<10><<<dim3(8, 2, cc), dim3(128), 0, stream>>>(
        (const void*)hA, hB, 992, nullptr, consts + 1024);
    // stage3: hB -> hA (Tout=988), dot2 path
    stage_kernel<10><<<dim3(8, 2, cc), dim3(128), 0, stream>>>(
        (const void*)hB, hA, 988, nullptr, consts + 2048);
    // conv4 + dense head (writes out[b] directly)
    final_kernel<<<dim3(cc), dim3(256), 0, stream>>>(
        hA, p[7], p[8], p[21], p[22], (float*)d_out, b0);
  }
}